// Round 13
// baseline (158.839 us; speedup 1.0000x reference)
//
#include <hip/hip_runtime.h>
#include <math.h>

#define BB   32
#define HH   56
#define WWI  56
#define CC   96
#define NHD  3
#define WSZ  7
#define SHF  3
#define NTK  49
#define NWIN 64
#define HDM  32
#define TOT  (BB*HH*WWI)               // 100352
#define QKSCALE 0.17677669529663687f
#define LEPS 1e-3f

typedef __attribute__((ext_vector_type(8))) short s8v;   // 8 bf16 (4 VGPRs)
typedef __attribute__((ext_vector_type(4))) float fx4;   // 4 fp32
typedef unsigned long long ull_t;

#define MFMA16(a,b,c) __builtin_amdgcn_mfma_f32_16x16x32_bf16((a),(b),(c),0,0,0)

__device__ __forceinline__ unsigned short f2bf(float f) {
    union { float f; unsigned u; } v; v.f = f;
    unsigned r = v.u + 0x7FFFu + ((v.u >> 16) & 1u);
    return (unsigned short)(r >> 16);
}

// sigmoid-form gelu (tanh approx): |err vs exact| <~2e-3, ~8 VALU ops vs ~28 for erff
__device__ __forceinline__ float gelu_t(float x) {
    float x3 = x * x * x;
    float z = -1.5957691216f * fmaf(0.044715f, x3, x);
    return x * __builtin_amdgcn_rcpf(1.f + __expf(z));
}

// windowed token id -> original flat token id (roll(-3,-3) + window partition)
__device__ __forceinline__ int wtok_to_orig(int wt) {
    int win = wt / NTK;
    int p   = wt - win * NTK;
    int b   = win >> 6;
    int w   = win & 63;
    int wi = w >> 3, wj = w & 7;
    int pi = p / WSZ, pj = p - pi * WSZ;
    int r = wi * WSZ + pi + SHF; if (r >= HH) r -= HH;
    int c = wj * WSZ + pj + SHF; if (c >= WWI) c -= WWI;
    return b * (HH * WWI) + r * WWI + c;
}

// LayerNorm in MFMA-A-fragment layout (reduction via shfl_xor 16/32)
__device__ __forceinline__ void ln_frag(const float* __restrict__ row,
                                        const float* __restrict__ gg,
                                        const float* __restrict__ bb,
                                        int g4, s8v ha[3])
{
    float h[24];
    #pragma unroll
    for (int ks = 0; ks < 3; ++ks) {
        fx4 v0 = *reinterpret_cast<const fx4*>(row + ks * 32 + g4 * 8);
        fx4 v1 = *reinterpret_cast<const fx4*>(row + ks * 32 + g4 * 8 + 4);
        h[ks*8+0]=v0.x; h[ks*8+1]=v0.y; h[ks*8+2]=v0.z; h[ks*8+3]=v0.w;
        h[ks*8+4]=v1.x; h[ks*8+5]=v1.y; h[ks*8+6]=v1.z; h[ks*8+7]=v1.w;
    }
    float s = 0.f, s2 = 0.f;
    #pragma unroll
    for (int j = 0; j < 24; ++j) { s += h[j]; s2 = fmaf(h[j], h[j], s2); }
    s  += __shfl_xor(s, 16);  s  += __shfl_xor(s, 32);
    s2 += __shfl_xor(s2, 16); s2 += __shfl_xor(s2, 32);
    const float mu = s * (1.f/CC);
    const float rs = rsqrtf(s2 * (1.f/CC) - mu * mu + LEPS);
    #pragma unroll
    for (int ks = 0; ks < 3; ++ks) {
        union { s8v v; unsigned short u[8]; } p;
        #pragma unroll
        for (int j = 0; j < 8; ++j) {
            int c = ks * 32 + g4 * 8 + j;
            p.u[j] = f2bf((h[ks*8+j] - mu) * rs * gg[c] + bb[c]);
        }
        ha[ks] = p.v;
    }
}

// ---------- P0: weight transpose/bf16 (QKSCALE folded into Q cols) + bias+mask ----------
extern "C" __global__ void p0_prep(const float* __restrict__ qw, const float* __restrict__ pw,
                                   const float* __restrict__ w1, const float* __restrict__ w2,
                                   const float* __restrict__ btab,
                                   unsigned short* __restrict__ wsw)
{
    int i = blockIdx.x * 256 + threadIdx.x;
    if (i < 27648) {                       // qwt[288][96]; Q cols (n<96) pre-scaled
        int n = i / 96, k = i - n * 96;
        float v = qw[k * 288 + n];
        if (n < 96) v *= QKSCALE;
        wsw[i] = f2bf(v);
    } else if (i < 36864) {                // pwt[96][96]
        int j = i - 27648; int n = j / 96, k = j - n * 96;
        wsw[i] = f2bf(pw[k * 96 + n]);
    } else if (i < 73728) {                // w1t[384][96]
        int j = i - 36864; int n = j / 96, k = j - n * 96;
        wsw[i] = f2bf(w1[k * 384 + n]);
    } else if (i < 110592) {               // w2t[96][384]
        int j = i - 73728; int n = j / 384, k = j - n * 384;
        wsw[i] = f2bf(w2[k * 96 + n]);
    } else if (i < 148224) {               // BM table (fp32)
        float* bm = (float*)(wsw + 110592);
        int j = i - 110592;
        int n = j & 63, mh = j >> 6;
        int m = mh % 49, t = mh / 49;
        int hd = t % 3, cls = t / 3;       // cls = (wi==7)*2 + (wj==7)
        float val = 0.f;
        if (n < 49) {
            int it = m / 7, jt = m - it * 7;
            int iu = n / 7, ju = n - iu * 7;
            int li  = (cls & 2) ? (it < 4 ? 1 : 2) : 0;
            int lj  = (cls & 1) ? (jt < 4 ? 1 : 2) : 0;
            int lui = (cls & 2) ? (iu < 4 ? 1 : 2) : 0;
            int luj = (cls & 1) ? (ju < 4 ? 1 : 2) : 0;
            int bidx = (jt - ju + 6) * 13 + (it - iu + 6);
            val = btab[bidx * 3 + hd] + ((li*3+lj) == (lui*3+luj) ? 0.f : -100.f);
        }
        bm[j] = val;
    }
}

// ---------- K1: gather + LN1(frag) + QKV MFMA; epilogue LDS-transposed to b128 stores ----------
#define LDH 104
#define LDO 104
extern "C" __global__ void __launch_bounds__(512, 4) k1_qkv(
    const float* __restrict__ x, const float* __restrict__ g1, const float* __restrict__ b1,
    const unsigned short* __restrict__ qwt, const float* __restrict__ qb,
    unsigned short* __restrict__ qkvb)
{
    __shared__ unsigned short Wc[96 * LDH];    // 19968 B
    __shared__ unsigned short Ot[128 * LDO];   // 26624 B (D-tile staging; 208B rows, 16B-aligned)
    const int tid = threadIdx.x, wave = tid >> 6, lane = tid & 63;
    const int l15 = lane & 15, g4 = lane >> 4;
    const int blk = blockIdx.x;

    s8v ha[3];
    {
        const int orig = wtok_to_orig(blk * 128 + wave * 16 + l15);
        ln_frag(x + (size_t)orig * CC, g1, b1, g4, ha);
    }

    for (int ck = 0; ck < 3; ++ck) {
        for (int i = tid; i < 96 * 12; i += 512) {
            int r = i / 12, k0 = (i - r * 12) * 8;
            *reinterpret_cast<s8v*>(&Wc[r * LDH + k0]) =
                *reinterpret_cast<const s8v*>(&qwt[(ck * 96 + r) * 96 + k0]);
        }
        __syncthreads();                       // A: Wc visible, prev Ot fully drained
        fx4 acc[6];
        #pragma unroll
        for (int nt = 0; nt < 6; ++nt) acc[nt] = (fx4){0.f,0.f,0.f,0.f};
        #pragma unroll
        for (int ks = 0; ks < 3; ++ks) {
            #pragma unroll
            for (int nt = 0; nt < 6; ++nt) {
                s8v b = *reinterpret_cast<const s8v*>(&Wc[(nt*16 + l15)*LDH + ks*32 + g4*8]);
                acc[nt] = MFMA16(ha[ks], b, acc[nt]);
            }
        }
        const float qmul = (ck == 0) ? QKSCALE : 1.f;   // qb scale matches scaled qwt
        #pragma unroll
        for (int nt = 0; nt < 6; ++nt) {
            const float qbc = qb[ck * 96 + nt * 16 + l15] * qmul;
            #pragma unroll
            for (int r = 0; r < 4; ++r)
                Ot[(wave*16 + g4*4 + r) * LDO + nt*16 + l15] = f2bf(acc[nt][r] + qbc);
        }
        __syncthreads();                       // B: Ot complete
        #pragma unroll
        for (int t = 0; t < 3; ++t) {          // 1536 s8v tile -> coalesced b128 stores
            int f = tid + t * 512;
            int tok = f / 12, c8 = f - tok * 12;
            *reinterpret_cast<s8v*>(&qkvb[(size_t)(blk * 128 + tok) * 288 + ck * 96 + c8 * 8]) =
                *reinterpret_cast<const s8v*>(&Ot[tok * LDO + c8 * 8]);
        }
    }
}

// ---------- K2: MFMA attention; V via coalesced-load + LDS transpose; O via b128 ----------
extern "C" __global__ void __launch_bounds__(64, 2) k2_attn(
    unsigned short* __restrict__ qkvb, const float* __restrict__ bm)
{
    __shared__ unsigned short P[64][72];   // 9216 B (reused as Ob[64][36] after PV)
    __shared__ unsigned short Vt[32][66];  // 4224 B (V^T: rows d, cols tok; pad 66)
    const int lane = threadIdx.x;
    const int l15 = lane & 15, g4 = lane >> 4;
    const int task = blockIdx.x;
    const int win = task / 3, h = task - win * 3;
    const int g0  = win * NTK;
    const int w   = win & 63;
    const int cls = (((w >> 3) == 7) ? 2 : 0) + (((w & 7) == 7) ? 1 : 0);
    const float* BMh = bm + ((size_t)(cls * 3 + h)) * 49 * 64;

    // stage V^T: coalesced b128 loads, b16 LDS scatter (pad cols zeroed)
    #pragma unroll
    for (int it = 0; it < 4; ++it) {
        int i = lane + it * 64;                // 0..255: tok = i>>2, chunk = i&3
        int tok = i >> 2, ch = i & 3;
        union { s8v v; unsigned short u[8]; } uv;
        uv.v = (s8v){0,0,0,0,0,0,0,0};
        if (tok < NTK)
            uv.v = *reinterpret_cast<const s8v*>(
                &qkvb[(size_t)(g0 + tok) * 288 + 192 + h * HDM + ch * 8]);
        #pragma unroll
        for (int j = 0; j < 8; ++j) Vt[ch * 8 + j][tok] = uv.u[j];
    }

    s8v aq[4], bk[4];
    #pragma unroll
    for (int mt = 0; mt < 4; ++mt) {
        int tok = mt * 16 + l15; if (tok > 48) tok = 48;
        const unsigned short* qp = &qkvb[(size_t)(g0 + tok) * 288 + h * HDM + g4 * 8];
        aq[mt] = *reinterpret_cast<const s8v*>(qp);        // Q (pre-scaled)
        bk[mt] = *reinterpret_cast<const s8v*>(qp + 96);   // K
    }

    fx4 sc[4][4];
    #pragma unroll
    for (int mt = 0; mt < 4; ++mt)
        #pragma unroll
        for (int nt = 0; nt < 4; ++nt)
            sc[mt][nt] = MFMA16(aq[mt], bk[nt], ((fx4){0.f,0.f,0.f,0.f}));

    #pragma unroll
    for (int mt = 0; mt < 4; ++mt) {
        #pragma unroll
        for (int r = 0; r < 4; ++r) {
            const int m = mt * 16 + g4 * 4 + r;
            const int mc = m > 48 ? 48 : m;
            float rs1 = 0.f;
            #pragma unroll
            for (int nt = 0; nt < 4; ++nt) {
                const int n = nt * 16 + l15;
                float s = sc[mt][nt][r] + BMh[mc * 64 + n];
                float e = (n < NTK) ? __expf(s) : 0.f;
                sc[mt][nt][r] = e;
                rs1 += e;
            }
            rs1 += __shfl_xor(rs1, 1); rs1 += __shfl_xor(rs1, 2);
            rs1 += __shfl_xor(rs1, 4); rs1 += __shfl_xor(rs1, 8);
            const float iv1 = 1.f / rs1;
            float rs2 = 0.f;
            #pragma unroll
            for (int nt = 0; nt < 4; ++nt) {
                const int n = nt * 16 + l15;
                float e2 = (n < NTK) ? __expf(sc[mt][nt][r] * iv1) : 0.f;
                sc[mt][nt][r] = e2;
                rs2 += e2;
            }
            rs2 += __shfl_xor(rs2, 1); rs2 += __shfl_xor(rs2, 2);
            rs2 += __shfl_xor(rs2, 4); rs2 += __shfl_xor(rs2, 8);
            const float iv2 = 1.f / rs2;
            #pragma unroll
            for (int nt = 0; nt < 4; ++nt)
                P[m][nt * 16 + l15] = f2bf(sc[mt][nt][r] * iv2);
        }
    }
    __syncthreads();

    fx4 oc[4][2];
    #pragma unroll
    for (int mt = 0; mt < 4; ++mt) { oc[mt][0] = (fx4){0.f,0.f,0.f,0.f}; oc[mt][1] = (fx4){0.f,0.f,0.f,0.f}; }
    #pragma unroll
    for (int ks = 0; ks < 2; ++ks) {
        s8v vb[2];
        #pragma unroll
        for (int nt = 0; nt < 2; ++nt)
            vb[nt] = *reinterpret_cast<const s8v*>(&Vt[nt * 16 + l15][ks * 32 + g4 * 8]);
        #pragma unroll
        for (int mt = 0; mt < 4; ++mt) {
            s8v pa = *reinterpret_cast<const s8v*>(&P[mt * 16 + l15][ks * 32 + g4 * 8]);
            oc[mt][0] = MFMA16(pa, vb[0], oc[mt][0]);
            oc[mt][1] = MFMA16(pa, vb[1], oc[mt][1]);
        }
    }
    // O -> Ob (reuse P region; single wave, in-order LDS) -> coalesced b128 stores
    unsigned short* Ob = &P[0][0];             // stride 36
    #pragma unroll
    for (int mt = 0; mt < 4; ++mt) {
        #pragma unroll
        for (int r = 0; r < 4; ++r) {
            const int m = mt * 16 + g4 * 4 + r;
            Ob[m * 36 + l15]      = f2bf(oc[mt][0][r]);
            Ob[m * 36 + 16 + l15] = f2bf(oc[mt][1][r]);
        }
    }
    #pragma unroll
    for (int it = 0; it < 4; ++it) {
        int i = lane + it * 64;
        if (i < 196) {                         // tok <= 48
            int tok = i >> 2, ch = i & 3;
            *reinterpret_cast<s8v*>(&qkvb[(size_t)(g0 + tok) * 288 + h * HDM + ch * 8]) =
                *reinterpret_cast<const s8v*>(&Ob[tok * 36 + ch * 8]);
        }
    }
}

// ---------- K2b: proj GEMM; A-frags direct from qkvb; LDS = Wc (unchanged R12) ----------
extern "C" __global__ void __launch_bounds__(512, 4) k2b_proj(
    const unsigned short* __restrict__ qkvb, const unsigned short* __restrict__ pwt,
    const float* __restrict__ pb, const float* __restrict__ x, float* __restrict__ out)
{
    __shared__ unsigned short Wc[96 * LDH];    // 19968 B
    const int tid = threadIdx.x, wave = tid >> 6, lane = tid & 63;
    const int l15 = lane & 15, g4 = lane >> 4;
    const int blk = blockIdx.x;

    for (int i = tid; i < 96 * 12; i += 512) {
        int r = i / 12, k0 = (i - r * 12) * 8;
        *reinterpret_cast<s8v*>(&Wc[r * LDH + k0]) =
            *reinterpret_cast<const s8v*>(&pwt[r * 96 + k0]);
    }
    const unsigned short* arow = qkvb + (size_t)(blk * 128 + wave * 16 + l15) * 288 + g4 * 8;
    s8v a0 = *reinterpret_cast<const s8v*>(arow);
    s8v a1 = *reinterpret_cast<const s8v*>(arow + 32);
    s8v a2 = *reinterpret_cast<const s8v*>(arow + 64);
    __syncthreads();

    fx4 acc[6];
    #pragma unroll
    for (int nt = 0; nt < 6; ++nt) acc[nt] = (fx4){0.f,0.f,0.f,0.f};
    #pragma unroll
    for (int nt = 0; nt < 6; ++nt) {
        acc[nt] = MFMA16(a0, *reinterpret_cast<const s8v*>(&Wc[(nt*16 + l15)*LDH +  0 + g4*8]), acc[nt]);
        acc[nt] = MFMA16(a1, *reinterpret_cast<const s8v*>(&Wc[(nt*16 + l15)*LDH + 32 + g4*8]), acc[nt]);
        acc[nt] = MFMA16(a2, *reinterpret_cast<const s8v*>(&Wc[(nt*16 + l15)*LDH + 64 + g4*8]), acc[nt]);
    }
    int orig[4];
    #pragma unroll
    for (int r = 0; r < 4; ++r)
        orig[r] = wtok_to_orig(blk * 128 + wave * 16 + g4 * 4 + r);
    #pragma unroll
    for (int nt = 0; nt < 6; ++nt) {
        const int col = nt * 16 + l15;
        const float pbc = pb[col];
        #pragma unroll
        for (int r = 0; r < 4; ++r) {
            const size_t idx = (size_t)orig[r] * CC + col;
            out[idx] = acc[nt][r] + pbc + x[idx];
        }
    }
}

// ---------- K3: LN2(frag) + fc1 + gelu_t^2 + fc2 + residual (unchanged R12) ----------
#define LDA 72
#define K3_LD(ck_, idx_, dst_) { \
    if ((idx_) < 768) { int r_ = (idx_) / 12, k0_ = ((idx_) - r_ * 12) * 8; \
        dst_ = *reinterpret_cast<const s8v*>(&w1t[((ck_) * 64 + r_) * 96 + k0_]); } \
    else { int j_ = (idx_) - 768; int r_ = j_ >> 3, k0_ = (j_ & 7) * 8; \
        dst_ = *reinterpret_cast<const s8v*>(&w2t[r_ * 384 + (ck_) * 64 + k0_]); } }
#define K3_ST(idx_, src_) { \
    if ((idx_) < 768) { int r_ = (idx_) / 12, k0_ = ((idx_) - r_ * 12) * 8; \
        *reinterpret_cast<s8v*>(&W1c[r_ * LDH + k0_]) = src_; } \
    else { int j_ = (idx_) - 768; int r_ = j_ >> 3, k0_ = (j_ & 7) * 8; \
        *reinterpret_cast<s8v*>(&W2c[r_ * LDA + k0_]) = src_; } }

extern "C" __global__ void __launch_bounds__(512, 4) k3_mlp(
    float* __restrict__ xio, const float* __restrict__ g2, const float* __restrict__ b2,
    const unsigned short* __restrict__ w1t, const float* __restrict__ bf1,
    const unsigned short* __restrict__ w2t, const float* __restrict__ bf2)
{
    __shared__ unsigned short W1c[64 * LDH];   // 13312 B
    __shared__ unsigned short Ac[128 * LDA];   // 18432 B (wave-private)
    __shared__ unsigned short W2c[96 * LDA];   // 13824 B  (total 45568 -> 3 blocks/CU)
    const int tid = threadIdx.x, wave = tid >> 6, lane = tid & 63;
    const int l15 = lane & 15, g4 = lane >> 4;
    const int blk = blockIdx.x;

    s8v ha[3];
    ln_frag(xio + (size_t)(blk * 128 + wave * 16 + l15) * CC, g2, b2, g4, ha);

    { // prologue: stage ck=0 weights
        s8v v0, v1, v2;
        K3_LD(0, tid, v0); K3_LD(0, tid + 512, v1); K3_LD(0, tid + 1024, v2);
        K3_ST(tid, v0); K3_ST(tid + 512, v1); K3_ST(tid + 1024, v2);
    }
    __syncthreads();

    fx4 oacc[6];
    #pragma unroll
    for (int nt = 0; nt < 6; ++nt) oacc[nt] = (fx4){0.f,0.f,0.f,0.f};

    for (int ck = 0; ck < 6; ++ck) {
        s8v n0, n1, n2;
        if (ck < 5) { K3_LD(ck + 1, tid, n0); K3_LD(ck + 1, tid + 512, n1); K3_LD(ck + 1, tid + 1024, n2); }

        fx4 a1[4];
        #pragma unroll
        for (int nt = 0; nt < 4; ++nt) a1[nt] = (fx4){0.f,0.f,0.f,0.f};
        #pragma unroll
        for (int ks = 0; ks < 3; ++ks) {
            #pragma unroll
            for (int nt = 0; nt < 4; ++nt) {
                s8v b = *reinterpret_cast<const s8v*>(&W1c[(nt*16 + l15)*LDH + ks*32 + g4*8]);
                a1[nt] = MFMA16(ha[ks], b, a1[nt]);
            }
        }
        #pragma unroll
        for (int nt = 0; nt < 4; ++nt) {
            const float bb = bf1[ck * 64 + nt * 16 + l15];
            #pragma unroll
            for (int r = 0; r < 4; ++r) {
                float v0 = a1[nt][r] + bb;
                Ac[(wave*16 + g4*4 + r) * LDA + nt*16 + l15] = f2bf(gelu_t(gelu_t(v0)));
            }
        }
        #pragma unroll
        for (int ks = 0; ks < 2; ++ks) {
            s8v a = *reinterpret_cast<const s8v*>(&Ac[(wave*16 + l15)*LDA + ks*32 + g4*8]);
            #pragma unroll
            for (int nt = 0; nt < 6; ++nt) {
                s8v b = *reinterpret_cast<const s8v*>(&W2c[(nt*16 + l15)*LDA + ks*32 + g4*8]);
                oacc[nt] = MFMA16(a, b, oacc[nt]);
            }
        }
        __syncthreads();
        if (ck < 5) {
            K3_ST(tid, n0); K3_ST(tid + 512, n1); K3_ST(tid + 1024, n2);
            __syncthreads();
        }
    }

    const int rowb = blk * 128 + wave * 16 + g4 * 4;
    #pragma unroll
    for (int nt = 0; nt < 6; ++nt) {
        const int col = nt * 16 + l15;
        const float bb = bf2[col];
        #pragma unroll
        for (int r = 0; r < 4; ++r) {
            const size_t idx = (size_t)(rowb + r) * CC + col;
            xio[idx] = xio[idx] + oacc[nt][r] + bb;
        }
    }
}

extern "C" void kernel_launch(void* const* d_in, const int* in_sizes, int n_in,
                              void* d_out, int out_size, void* d_ws, size_t ws_size,
                              hipStream_t stream)
{
    const float* x    = (const float*)d_in[0];
    const float* n1g  = (const float*)d_in[1];
    const float* n1b  = (const float*)d_in[2];
    const float* qw   = (const float*)d_in[3];
    const float* qb   = (const float*)d_in[4];
    const float* btab = (const float*)d_in[5];
    const float* pw   = (const float*)d_in[6];
    const float* pb   = (const float*)d_in[7];
    const float* n2g  = (const float*)d_in[8];
    const float* n2b  = (const float*)d_in[9];
    const float* w1   = (const float*)d_in[10];
    const float* bf1  = (const float*)d_in[11];
    const float* w2   = (const float*)d_in[12];
    const float* bf2  = (const float*)d_in[13];
    float* out = (float*)d_out;

    unsigned short* qkvb = (unsigned short*)d_ws;                 // TOT*288 bf16 = 57.8 MB
    unsigned short* wbf = qkvb + (size_t)TOT * 288;
    unsigned short* qwt = wbf;
    unsigned short* pwt = qwt + 288 * 96;
    unsigned short* w1t = pwt + 96 * 96;
    unsigned short* w2t = w1t + 384 * 96;
    float* bmt = (float*)(wbf + 110592);                          // [4][3][49][64]

    p0_prep <<<579, 256, 0, stream>>>(qw, pw, w1, w2, btab, wbf);
    k1_qkv  <<<TOT/128, 512, 0, stream>>>(x, n1g, n1b, qwt, qb, qkvb);
    k2_attn <<<BB*NWIN*NHD, 64, 0, stream>>>(qkvb, bmt);
    k2b_proj<<<TOT/128, 512, 0, stream>>>(qkvb, pwt, pb, x, out);
    k3_mlp  <<<TOT/128, 512, 0, stream>>>(out, n2g, n2b, w1t, bf1, w2t, bf2);
}

// Round 14
// 152.948 us; speedup vs baseline: 1.0385x; 1.0385x over previous
//
#include <hip/hip_runtime.h>
#include <math.h>

#define BB   32
#define HH   56
#define WWI  56
#define CC   96
#define NHD  3
#define WSZ  7
#define SHF  3
#define NTK  49
#define NWIN 64
#define HDM  32
#define TOT  (BB*HH*WWI)               // 100352
#define QKSCALE 0.17677669529663687f
#define LEPS 1e-3f

typedef __attribute__((ext_vector_type(8))) short s8v;   // 8 bf16 (4 VGPRs)
typedef __attribute__((ext_vector_type(4))) float fx4;   // 4 fp32
typedef unsigned long long ull_t;

#define MFMA16(a,b,c) __builtin_amdgcn_mfma_f32_16x16x32_bf16((a),(b),(c),0,0,0)

__device__ __forceinline__ unsigned short f2bf(float f) {
    union { float f; unsigned u; } v; v.f = f;
    unsigned r = v.u + 0x7FFFu + ((v.u >> 16) & 1u);
    return (unsigned short)(r >> 16);
}

// sigmoid-form gelu (tanh approx): |err vs exact| <~2e-3, ~8 VALU ops vs ~28 for erff
__device__ __forceinline__ float gelu_t(float x) {
    float x3 = x * x * x;
    float z = -1.5957691216f * fmaf(0.044715f, x3, x);
    return x * __builtin_amdgcn_rcpf(1.f + __expf(z));
}

// windowed token id -> original flat token id (roll(-3,-3) + window partition)
__device__ __forceinline__ int wtok_to_orig(int wt) {
    int win = wt / NTK;
    int p   = wt - win * NTK;
    int b   = win >> 6;
    int w   = win & 63;
    int wi = w >> 3, wj = w & 7;
    int pi = p / WSZ, pj = p - pi * WSZ;
    int r = wi * WSZ + pi + SHF; if (r >= HH) r -= HH;
    int c = wj * WSZ + pj + SHF; if (c >= WWI) c -= WWI;
    return b * (HH * WWI) + r * WWI + c;
}

// LayerNorm in MFMA-A-fragment layout (reduction via shfl_xor 16/32)
__device__ __forceinline__ void ln_frag(const float* __restrict__ row,
                                        const float* __restrict__ gg,
                                        const float* __restrict__ bb,
                                        int g4, s8v ha[3])
{
    float h[24];
    #pragma unroll
    for (int ks = 0; ks < 3; ++ks) {
        fx4 v0 = *reinterpret_cast<const fx4*>(row + ks * 32 + g4 * 8);
        fx4 v1 = *reinterpret_cast<const fx4*>(row + ks * 32 + g4 * 8 + 4);
        h[ks*8+0]=v0.x; h[ks*8+1]=v0.y; h[ks*8+2]=v0.z; h[ks*8+3]=v0.w;
        h[ks*8+4]=v1.x; h[ks*8+5]=v1.y; h[ks*8+6]=v1.z; h[ks*8+7]=v1.w;
    }
    float s = 0.f, s2 = 0.f;
    #pragma unroll
    for (int j = 0; j < 24; ++j) { s += h[j]; s2 = fmaf(h[j], h[j], s2); }
    s  += __shfl_xor(s, 16);  s  += __shfl_xor(s, 32);
    s2 += __shfl_xor(s2, 16); s2 += __shfl_xor(s2, 32);
    const float mu = s * (1.f/CC);
    const float rs = rsqrtf(s2 * (1.f/CC) - mu * mu + LEPS);
    #pragma unroll
    for (int ks = 0; ks < 3; ++ks) {
        union { s8v v; unsigned short u[8]; } p;
        #pragma unroll
        for (int j = 0; j < 8; ++j) {
            int c = ks * 32 + g4 * 8 + j;
            p.u[j] = f2bf((h[ks*8+j] - mu) * rs * gg[c] + bb[c]);
        }
        ha[ks] = p.v;
    }
}

// ---------- P0: weight transpose/bf16 (QKSCALE folded into Q cols) + bias+mask ----------
extern "C" __global__ void p0_prep(const float* __restrict__ qw, const float* __restrict__ pw,
                                   const float* __restrict__ w1, const float* __restrict__ w2,
                                   const float* __restrict__ btab,
                                   unsigned short* __restrict__ wsw)
{
    int i = blockIdx.x * 256 + threadIdx.x;
    if (i < 27648) {                       // qwt[288][96]; Q cols (n<96) pre-scaled
        int n = i / 96, k = i - n * 96;
        float v = qw[k * 288 + n];
        if (n < 96) v *= QKSCALE;
        wsw[i] = f2bf(v);
    } else if (i < 36864) {                // pwt[96][96]
        int j = i - 27648; int n = j / 96, k = j - n * 96;
        wsw[i] = f2bf(pw[k * 96 + n]);
    } else if (i < 73728) {                // w1t[384][96]
        int j = i - 36864; int n = j / 96, k = j - n * 96;
        wsw[i] = f2bf(w1[k * 384 + n]);
    } else if (i < 110592) {               // w2t[96][384]
        int j = i - 73728; int n = j / 384, k = j - n * 384;
        wsw[i] = f2bf(w2[k * 96 + n]);
    } else if (i < 148224) {               // BM table (fp32)
        float* bm = (float*)(wsw + 110592);
        int j = i - 110592;
        int n = j & 63, mh = j >> 6;
        int m = mh % 49, t = mh / 49;
        int hd = t % 3, cls = t / 3;       // cls = (wi==7)*2 + (wj==7)
        float val = 0.f;
        if (n < 49) {
            int it = m / 7, jt = m - it * 7;
            int iu = n / 7, ju = n - iu * 7;
            int li  = (cls & 2) ? (it < 4 ? 1 : 2) : 0;
            int lj  = (cls & 1) ? (jt < 4 ? 1 : 2) : 0;
            int lui = (cls & 2) ? (iu < 4 ? 1 : 2) : 0;
            int luj = (cls & 1) ? (ju < 4 ? 1 : 2) : 0;
            int bidx = (jt - ju + 6) * 13 + (it - iu + 6);
            val = btab[bidx * 3 + hd] + ((li*3+lj) == (lui*3+luj) ? 0.f : -100.f);
        }
        bm[j] = val;
    }
}

// ---------- K1: gather + LN1(frag) + QKV MFMA GEMM -> qkvb bf16 (R12 form) ----------
#define LDH 104
extern "C" __global__ void __launch_bounds__(512, 4) k1_qkv(
    const float* __restrict__ x, const float* __restrict__ g1, const float* __restrict__ b1,
    const unsigned short* __restrict__ qwt, const float* __restrict__ qb,
    unsigned short* __restrict__ qkvb)
{
    __shared__ unsigned short Wc[96 * LDH];    // 19968 B
    const int tid = threadIdx.x, wave = tid >> 6, lane = tid & 63;
    const int l15 = lane & 15, g4 = lane >> 4;
    const int blk = blockIdx.x;

    s8v ha[3];
    {
        const int orig = wtok_to_orig(blk * 128 + wave * 16 + l15);
        ln_frag(x + (size_t)orig * CC, g1, b1, g4, ha);
    }

    for (int ck = 0; ck < 3; ++ck) {
        for (int i = tid; i < 96 * 12; i += 512) {
            int r = i / 12, k0 = (i - r * 12) * 8;
            *reinterpret_cast<s8v*>(&Wc[r * LDH + k0]) =
                *reinterpret_cast<const s8v*>(&qwt[(ck * 96 + r) * 96 + k0]);
        }
        __syncthreads();
        fx4 acc[6];
        #pragma unroll
        for (int nt = 0; nt < 6; ++nt) acc[nt] = (fx4){0.f,0.f,0.f,0.f};
        #pragma unroll
        for (int ks = 0; ks < 3; ++ks) {
            #pragma unroll
            for (int nt = 0; nt < 6; ++nt) {
                s8v b = *reinterpret_cast<const s8v*>(&Wc[(nt*16 + l15)*LDH + ks*32 + g4*8]);
                acc[nt] = MFMA16(ha[ks], b, acc[nt]);
            }
        }
        const int rowb = blk * 128 + wave * 16 + g4 * 4;
        const float qmul = (ck == 0) ? QKSCALE : 1.f;   // qb scale matches scaled qwt
        #pragma unroll
        for (int nt = 0; nt < 6; ++nt) {
            const int col = ck * 96 + nt * 16 + l15;
            const float qbc = qb[col] * qmul;
            #pragma unroll
            for (int r = 0; r < 4; ++r)
                qkvb[(size_t)(rowb + r) * 288 + col] = f2bf(acc[nt][r] + qbc);
        }
        __syncthreads();
    }
}

// ---------- K2: MFMA attention on bf16 qkv (R12 form) ----------
extern "C" __global__ void __launch_bounds__(64, 2) k2_attn(
    unsigned short* __restrict__ qkvb, const float* __restrict__ bm)
{
    __shared__ unsigned short P[64][72];   // 9216 B
    const int lane = threadIdx.x;
    const int l15 = lane & 15, g4 = lane >> 4;
    const int task = blockIdx.x;
    const int win = task / 3, h = task - win * 3;
    const int g0  = win * NTK;
    const int w   = win & 63;
    const int cls = (((w >> 3) == 7) ? 2 : 0) + (((w & 7) == 7) ? 1 : 0);
    const float* BMh = bm + ((size_t)(cls * 3 + h)) * 49 * 64;

    s8v aq[4], bk[4];
    #pragma unroll
    for (int mt = 0; mt < 4; ++mt) {
        int tok = mt * 16 + l15; if (tok > 48) tok = 48;
        const unsigned short* qp = &qkvb[(size_t)(g0 + tok) * 288 + h * HDM + g4 * 8];
        aq[mt] = *reinterpret_cast<const s8v*>(qp);        // Q (pre-scaled)
        bk[mt] = *reinterpret_cast<const s8v*>(qp + 96);   // K
    }

    fx4 sc[4][4];
    #pragma unroll
    for (int mt = 0; mt < 4; ++mt)
        #pragma unroll
        for (int nt = 0; nt < 4; ++nt)
            sc[mt][nt] = MFMA16(aq[mt], bk[nt], ((fx4){0.f,0.f,0.f,0.f}));

    #pragma unroll
    for (int mt = 0; mt < 4; ++mt) {
        #pragma unroll
        for (int r = 0; r < 4; ++r) {
            const int m = mt * 16 + g4 * 4 + r;
            const int mc = m > 48 ? 48 : m;
            float rs1 = 0.f;
            #pragma unroll
            for (int nt = 0; nt < 4; ++nt) {
                const int n = nt * 16 + l15;
                float s = sc[mt][nt][r] + BMh[mc * 64 + n];
                float e = (n < NTK) ? __expf(s) : 0.f;
                sc[mt][nt][r] = e;
                rs1 += e;
            }
            rs1 += __shfl_xor(rs1, 1); rs1 += __shfl_xor(rs1, 2);
            rs1 += __shfl_xor(rs1, 4); rs1 += __shfl_xor(rs1, 8);
            const float iv1 = 1.f / rs1;
            float rs2 = 0.f;
            #pragma unroll
            for (int nt = 0; nt < 4; ++nt) {
                const int n = nt * 16 + l15;
                float e2 = (n < NTK) ? __expf(sc[mt][nt][r] * iv1) : 0.f;
                sc[mt][nt][r] = e2;
                rs2 += e2;
            }
            rs2 += __shfl_xor(rs2, 1); rs2 += __shfl_xor(rs2, 2);
            rs2 += __shfl_xor(rs2, 4); rs2 += __shfl_xor(rs2, 8);
            const float iv2 = 1.f / rs2;
            #pragma unroll
            for (int nt = 0; nt < 4; ++nt)
                P[m][nt * 16 + l15] = f2bf(sc[mt][nt][r] * iv2);
        }
    }
    __syncthreads();

    fx4 oc[4][2];
    #pragma unroll
    for (int mt = 0; mt < 4; ++mt) { oc[mt][0] = (fx4){0.f,0.f,0.f,0.f}; oc[mt][1] = (fx4){0.f,0.f,0.f,0.f}; }
    #pragma unroll
    for (int ks = 0; ks < 2; ++ks) {
        s8v vb[2];
        #pragma unroll
        for (int nt = 0; nt < 2; ++nt) {
            union { s8v v; unsigned short u[8]; } pv;
            #pragma unroll
            for (int j = 0; j < 8; ++j) {
                int tok = ks * 32 + g4 * 8 + j; if (tok > 48) tok = 48;
                pv.u[j] = qkvb[(size_t)(g0 + tok) * 288 + 192 + h * HDM + nt * 16 + l15];
            }
            vb[nt] = pv.v;
        }
        #pragma unroll
        for (int mt = 0; mt < 4; ++mt) {
            s8v pa = *reinterpret_cast<const s8v*>(&P[mt * 16 + l15][ks * 32 + g4 * 8]);
            oc[mt][0] = MFMA16(pa, vb[0], oc[mt][0]);
            oc[mt][1] = MFMA16(pa, vb[1], oc[mt][1]);
        }
    }
    #pragma unroll
    for (int mt = 0; mt < 4; ++mt) {
        #pragma unroll
        for (int r = 0; r < 4; ++r) {
            const int m = mt * 16 + g4 * 4 + r;
            if (m < NTK) {
                qkvb[(size_t)(g0 + m) * 288 + h * HDM + l15]      = f2bf(oc[mt][0][r]);
                qkvb[(size_t)(g0 + m) * 288 + h * HDM + 16 + l15] = f2bf(oc[mt][1][r]);
            }
        }
    }
}

// ---------- K2b: proj GEMM; A-frags direct from qkvb; LDS = Wc (R12 form) ----------
extern "C" __global__ void __launch_bounds__(512, 4) k2b_proj(
    const unsigned short* __restrict__ qkvb, const unsigned short* __restrict__ pwt,
    const float* __restrict__ pb, const float* __restrict__ x, float* __restrict__ out)
{
    __shared__ unsigned short Wc[96 * LDH];    // 19968 B
    const int tid = threadIdx.x, wave = tid >> 6, lane = tid & 63;
    const int l15 = lane & 15, g4 = lane >> 4;
    const int blk = blockIdx.x;

    for (int i = tid; i < 96 * 12; i += 512) {
        int r = i / 12, k0 = (i - r * 12) * 8;
        *reinterpret_cast<s8v*>(&Wc[r * LDH + k0]) =
            *reinterpret_cast<const s8v*>(&pwt[r * 96 + k0]);
    }
    const unsigned short* arow = qkvb + (size_t)(blk * 128 + wave * 16 + l15) * 288 + g4 * 8;
    s8v a0 = *reinterpret_cast<const s8v*>(arow);
    s8v a1 = *reinterpret_cast<const s8v*>(arow + 32);
    s8v a2 = *reinterpret_cast<const s8v*>(arow + 64);
    __syncthreads();

    fx4 acc[6];
    #pragma unroll
    for (int nt = 0; nt < 6; ++nt) acc[nt] = (fx4){0.f,0.f,0.f,0.f};
    #pragma unroll
    for (int nt = 0; nt < 6; ++nt) {
        acc[nt] = MFMA16(a0, *reinterpret_cast<const s8v*>(&Wc[(nt*16 + l15)*LDH +  0 + g4*8]), acc[nt]);
        acc[nt] = MFMA16(a1, *reinterpret_cast<const s8v*>(&Wc[(nt*16 + l15)*LDH + 32 + g4*8]), acc[nt]);
        acc[nt] = MFMA16(a2, *reinterpret_cast<const s8v*>(&Wc[(nt*16 + l15)*LDH + 64 + g4*8]), acc[nt]);
    }
    int orig[4];
    #pragma unroll
    for (int r = 0; r < 4; ++r)
        orig[r] = wtok_to_orig(blk * 128 + wave * 16 + g4 * 4 + r);
    #pragma unroll
    for (int nt = 0; nt < 6; ++nt) {
        const int col = nt * 16 + l15;
        const float pbc = pb[col];
        #pragma unroll
        for (int r = 0; r < 4; ++r) {
            const size_t idx = (size_t)orig[r] * CC + col;
            out[idx] = acc[nt][r] + pbc + x[idx];
        }
    }
}

// ---------- K3: LN2(frag) + fc1 + gelu_t^2 + fc2 + residual ----------
// 256 threads, 128 tokens: each wave owns TWO independent 16-token tiles.
// The two chains interleave (gelu VALU of one overlaps MFMA of the other),
// every W1c/W2c B-frag read feeds 2 MFMAs, barriers per token halve.
// LDS 45.5 KB -> 3 blocks/CU. (256,2): ~150 live VGPR, keep 256-reg budget.
#define LDA 72
#define K3_LD(ck_, idx_, dst_) { \
    if ((idx_) < 768) { int r_ = (idx_) / 12, k0_ = ((idx_) - r_ * 12) * 8; \
        dst_ = *reinterpret_cast<const s8v*>(&w1t[((ck_) * 64 + r_) * 96 + k0_]); } \
    else { int j_ = (idx_) - 768; int r_ = j_ >> 3, k0_ = (j_ & 7) * 8; \
        dst_ = *reinterpret_cast<const s8v*>(&w2t[r_ * 384 + (ck_) * 64 + k0_]); } }
#define K3_ST(idx_, src_) { \
    if ((idx_) < 768) { int r_ = (idx_) / 12, k0_ = ((idx_) - r_ * 12) * 8; \
        *reinterpret_cast<s8v*>(&W1c[r_ * LDH + k0_]) = src_; } \
    else { int j_ = (idx_) - 768; int r_ = j_ >> 3, k0_ = (j_ & 7) * 8; \
        *reinterpret_cast<s8v*>(&W2c[r_ * LDA + k0_]) = src_; } }

extern "C" __global__ void __launch_bounds__(256, 2) k3_mlp(
    float* __restrict__ xio, const float* __restrict__ g2, const float* __restrict__ b2,
    const unsigned short* __restrict__ w1t, const float* __restrict__ bf1,
    const unsigned short* __restrict__ w2t, const float* __restrict__ bf2)
{
    __shared__ unsigned short W1c[64 * LDH];   // 13312 B
    __shared__ unsigned short Ac[128 * LDA];   // 18432 B (wave-private rows)
    __shared__ unsigned short W2c[96 * LDA];   // 13824 B  (total 45568 -> 3 blocks/CU)
    const int tid = threadIdx.x, wave = tid >> 6, lane = tid & 63;
    const int l15 = lane & 15, g4 = lane >> 4;
    const int blk = blockIdx.x;
    const int row0 = blk * 128 + wave * 32;    // this wave's 32 tokens

    s8v ha0[3], ha1[3];
    ln_frag(xio + (size_t)(row0 + l15) * CC,      g2, b2, g4, ha0);
    ln_frag(xio + (size_t)(row0 + 16 + l15) * CC, g2, b2, g4, ha1);

    { // prologue: stage ck=0 weights (1536 s8v / 256 threads = 6 each)
        s8v v[6];
        #pragma unroll
        for (int k = 0; k < 6; ++k) K3_LD(0, tid + k * 256, v[k]);
        #pragma unroll
        for (int k = 0; k < 6; ++k) K3_ST(tid + k * 256, v[k]);
    }
    __syncthreads();

    fx4 oa0[6], oa1[6];
    #pragma unroll
    for (int nt = 0; nt < 6; ++nt) { oa0[nt] = (fx4){0.f,0.f,0.f,0.f}; oa1[nt] = (fx4){0.f,0.f,0.f,0.f}; }

    for (int ck = 0; ck < 6; ++ck) {
        // T14: issue next chunk's global loads; land under compute
        s8v n0, n1, n2, n3, n4, n5;
        if (ck < 5) {
            K3_LD(ck + 1, tid,        n0); K3_LD(ck + 1, tid + 256,  n1);
            K3_LD(ck + 1, tid + 512,  n2); K3_LD(ck + 1, tid + 768,  n3);
            K3_LD(ck + 1, tid + 1024, n4); K3_LD(ck + 1, tid + 1280, n5);
        }

        // fc1: two tiles share every B-frag
        fx4 a10[4], a11[4];
        #pragma unroll
        for (int nt = 0; nt < 4; ++nt) { a10[nt] = (fx4){0.f,0.f,0.f,0.f}; a11[nt] = (fx4){0.f,0.f,0.f,0.f}; }
        #pragma unroll
        for (int ks = 0; ks < 3; ++ks) {
            #pragma unroll
            for (int nt = 0; nt < 4; ++nt) {
                s8v b = *reinterpret_cast<const s8v*>(&W1c[(nt*16 + l15)*LDH + ks*32 + g4*8]);
                a10[nt] = MFMA16(ha0[ks], b, a10[nt]);
                a11[nt] = MFMA16(ha1[ks], b, a11[nt]);
            }
        }
        // gelu^2 -> Ac (wave-private rows: no barrier before fc2)
        #pragma unroll
        for (int nt = 0; nt < 4; ++nt) {
            const float bb = bf1[ck * 64 + nt * 16 + l15];
            #pragma unroll
            for (int r = 0; r < 4; ++r) {
                float v0 = a10[nt][r] + bb;
                float v1 = a11[nt][r] + bb;
                Ac[(wave*32 +      g4*4 + r) * LDA + nt*16 + l15] = f2bf(gelu_t(gelu_t(v0)));
                Ac[(wave*32 + 16 + g4*4 + r) * LDA + nt*16 + l15] = f2bf(gelu_t(gelu_t(v1)));
            }
        }
        // fc2: two tiles share every B-frag
        #pragma unroll
        for (int ks = 0; ks < 2; ++ks) {
            s8v aA = *reinterpret_cast<const s8v*>(&Ac[(wave*32 +      l15)*LDA + ks*32 + g4*8]);
            s8v aB = *reinterpret_cast<const s8v*>(&Ac[(wave*32 + 16 + l15)*LDA + ks*32 + g4*8]);
            #pragma unroll
            for (int nt = 0; nt < 6; ++nt) {
                s8v b = *reinterpret_cast<const s8v*>(&W2c[(nt*16 + l15)*LDA + ks*32 + g4*8]);
                oa0[nt] = MFMA16(aA, b, oa0[nt]);
                oa1[nt] = MFMA16(aB, b, oa1[nt]);
            }
        }
        __syncthreads();                 // all waves done reading W1c/W2c
        if (ck < 5) {
            K3_ST(tid,        n0); K3_ST(tid + 256,  n1);
            K3_ST(tid + 512,  n2); K3_ST(tid + 768,  n3);
            K3_ST(tid + 1024, n4); K3_ST(tid + 1280, n5);
            __syncthreads();             // new W visible to all waves
        }
    }

    #pragma unroll
    for (int u = 0; u < 2; ++u) {
        const int rowb = row0 + u * 16 + g4 * 4;
        #pragma unroll
        for (int nt = 0; nt < 6; ++nt) {
            const int col = nt * 16 + l15;
            const float bb = bf2[col];
            #pragma unroll
            for (int r = 0; r < 4; ++r) {
                const size_t idx = (size_t)(rowb + r) * CC + col;
                const float ov = (u == 0) ? oa0[nt][r] : oa1[nt][r];
                xio[idx] = xio[idx] + ov + bb;
            }
        }
    }
}

extern "C" void kernel_launch(void* const* d_in, const int* in_sizes, int n_in,
                              void* d_out, int out_size, void* d_ws, size_t ws_size,
                              hipStream_t stream)
{
    const float* x    = (const float*)d_in[0];
    const float* n1g  = (const float*)d_in[1];
    const float* n1b  = (const float*)d_in[2];
    const float* qw   = (const float*)d_in[3];
    const float* qb   = (const float*)d_in[4];
    const float* btab = (const float*)d_in[5];
    const float* pw   = (const float*)d_in[6];
    const float* pb   = (const float*)d_in[7];
    const float* n2g  = (const float*)d_in[8];
    const float* n2b  = (const float*)d_in[9];
    const float* w1   = (const float*)d_in[10];
    const float* bf1  = (const float*)d_in[11];
    const float* w2   = (const float*)d_in[12];
    const float* bf2  = (const float*)d_in[13];
    float* out = (float*)d_out;

    unsigned short* qkvb = (unsigned short*)d_ws;                 // TOT*288 bf16 = 57.8 MB
    unsigned short* wbf = qkvb + (size_t)TOT * 288;
    unsigned short* qwt = wbf;
    unsigned short* pwt = qwt + 288 * 96;
    unsigned short* w1t = pwt + 96 * 96;
    unsigned short* w2t = w1t + 384 * 96;
    float* bmt = (float*)(wbf + 110592);                          // [4][3][49][64]

    p0_prep <<<579, 256, 0, stream>>>(qw, pw, w1, w2, btab, wbf);
    k1_qkv  <<<TOT/128, 512, 0, stream>>>(x, n1g, n1b, qwt, qb, qkvb);
    k2_attn <<<BB*NWIN*NHD, 64, 0, stream>>>(qkvb, bmt);
    k2b_proj<<<TOT/128, 512, 0, stream>>>(qkvb, pwt, pb, x, out);
    k3_mlp  <<<TOT/128, 256, 0, stream>>>(out, n2g, n2b, w1t, bf1, w2t, bf2);
}

// Round 15
// 141.330 us; speedup vs baseline: 1.1239x; 1.0822x over previous
//
#include <hip/hip_runtime.h>
#include <math.h>

#define BB   32
#define HH   56
#define WWI  56
#define CC   96
#define NHD  3
#define WSZ  7
#define SHF  3
#define NTK  49
#define NWIN 64
#define HDM  32
#define TOT  (BB*HH*WWI)               // 100352
#define QKSCALE 0.17677669529663687f
#define LEPS 1e-3f

typedef __attribute__((ext_vector_type(8))) short s8v;   // 8 bf16 (4 VGPRs)
typedef __attribute__((ext_vector_type(4))) float fx4;   // 4 fp32
typedef unsigned long long ull_t;

#define MFMA16(a,b,c) __builtin_amdgcn_mfma_f32_16x16x32_bf16((a),(b),(c),0,0,0)

__device__ __forceinline__ unsigned short f2bf(float f) {
    union { float f; unsigned u; } v; v.f = f;
    unsigned r = v.u + 0x7FFFu + ((v.u >> 16) & 1u);
    return (unsigned short)(r >> 16);
}

// sigmoid-form gelu (tanh approx): |err vs exact| <~2e-3, ~8 VALU ops vs ~28 for erff
__device__ __forceinline__ float gelu_t(float x) {
    float x3 = x * x * x;
    float z = -1.5957691216f * fmaf(0.044715f, x3, x);
    return x * __builtin_amdgcn_rcpf(1.f + __expf(z));
}

// windowed token id -> original flat token id (roll(-3,-3) + window partition)
__device__ __forceinline__ int wtok_to_orig(int wt) {
    int win = wt / NTK;
    int p   = wt - win * NTK;
    int b   = win >> 6;
    int w   = win & 63;
    int wi = w >> 3, wj = w & 7;
    int pi = p / WSZ, pj = p - pi * WSZ;
    int r = wi * WSZ + pi + SHF; if (r >= HH) r -= HH;
    int c = wj * WSZ + pj + SHF; if (c >= WWI) c -= WWI;
    return b * (HH * WWI) + r * WWI + c;
}

// LayerNorm in MFMA-A-fragment layout (reduction via shfl_xor 16/32)
__device__ __forceinline__ void ln_frag(const float* __restrict__ row,
                                        const float* __restrict__ gg,
                                        const float* __restrict__ bb,
                                        int g4, s8v ha[3])
{
    float h[24];
    #pragma unroll
    for (int ks = 0; ks < 3; ++ks) {
        fx4 v0 = *reinterpret_cast<const fx4*>(row + ks * 32 + g4 * 8);
        fx4 v1 = *reinterpret_cast<const fx4*>(row + ks * 32 + g4 * 8 + 4);
        h[ks*8+0]=v0.x; h[ks*8+1]=v0.y; h[ks*8+2]=v0.z; h[ks*8+3]=v0.w;
        h[ks*8+4]=v1.x; h[ks*8+5]=v1.y; h[ks*8+6]=v1.z; h[ks*8+7]=v1.w;
    }
    float s = 0.f, s2 = 0.f;
    #pragma unroll
    for (int j = 0; j < 24; ++j) { s += h[j]; s2 = fmaf(h[j], h[j], s2); }
    s  += __shfl_xor(s, 16);  s  += __shfl_xor(s, 32);
    s2 += __shfl_xor(s2, 16); s2 += __shfl_xor(s2, 32);
    const float mu = s * (1.f/CC);
    const float rs = rsqrtf(s2 * (1.f/CC) - mu * mu + LEPS);
    #pragma unroll
    for (int ks = 0; ks < 3; ++ks) {
        union { s8v v; unsigned short u[8]; } p;
        #pragma unroll
        for (int j = 0; j < 8; ++j) {
            int c = ks * 32 + g4 * 8 + j;
            p.u[j] = f2bf((h[ks*8+j] - mu) * rs * gg[c] + bb[c]);
        }
        ha[ks] = p.v;
    }
}

// ---------- P0: weight prep ----------
// qwt[288][96] row-major (QKSCALE folded into Q cols) | w1f frag-linear |
// w2f frag-linear | pwt[96][96] | BM table.
// Frag-linear: one wave's MFMA B-fragment is CONTIGUOUS 1KB:
//   w1f[((ck*4+nt)*3+ks)*512 + lane*8 + j] = w1[k*384 + n],
//     n = ck*64+nt*16+(lane&15), k = ks*32+(lane>>4)*8+j
//   w2f[((ck*6+nt)*2+ks)*512 + lane*8 + j] = w2[k*96 + n],
//     n = nt*16+(lane&15), k = ck*64+ks*32+(lane>>4)*8+j
extern "C" __global__ void p0_prep(const float* __restrict__ qw, const float* __restrict__ pw,
                                   const float* __restrict__ w1, const float* __restrict__ w2,
                                   const float* __restrict__ btab,
                                   unsigned short* __restrict__ wsw)
{
    int i = blockIdx.x * 256 + threadIdx.x;
    if (i < 27648) {                       // qwt[288][96]; Q cols (n<96) pre-scaled
        int n = i / 96, k = i - n * 96;
        float v = qw[k * 288 + n];
        if (n < 96) v *= QKSCALE;
        wsw[i] = f2bf(v);
    } else if (i < 36864) {                // pwt[96][96]
        int j = i - 27648; int n = j / 96, k = j - n * 96;
        wsw[i] = f2bf(pw[k * 96 + n]);
    } else if (i < 73728) {                // w1f frag-linear [36864]
        int j = i - 36864;
        int e = j & 7, f = j >> 3;
        int lane = f & 63, fid = f >> 6;
        int ks = fid % 3, t = fid / 3;
        int nt = t & 3, ck = t >> 2;
        int n = ck * 64 + nt * 16 + (lane & 15);
        int k = ks * 32 + (lane >> 4) * 8 + e;
        wsw[i] = f2bf(w1[k * 384 + n]);
    } else if (i < 110592) {               // w2f frag-linear [36864]
        int j = i - 73728;
        int e = j & 7, f = j >> 3;
        int lane = f & 63, fid = f >> 6;
        int ks = fid & 1, t = fid >> 1;
        int nt = t % 6, ck = t / 6;
        int n = nt * 16 + (lane & 15);
        int k = ck * 64 + ks * 32 + (lane >> 4) * 8 + e;
        wsw[i] = f2bf(w2[k * 96 + n]);
    } else if (i < 148224) {               // BM table (fp32)
        float* bm = (float*)(wsw + 110592);
        int j = i - 110592;
        int n = j & 63, mh = j >> 6;
        int m = mh % 49, t = mh / 49;
        int hd = t % 3, cls = t / 3;       // cls = (wi==7)*2 + (wj==7)
        float val = 0.f;
        if (n < 49) {
            int it = m / 7, jt = m - it * 7;
            int iu = n / 7, ju = n - iu * 7;
            int li  = (cls & 2) ? (it < 4 ? 1 : 2) : 0;
            int lj  = (cls & 1) ? (jt < 4 ? 1 : 2) : 0;
            int lui = (cls & 2) ? (iu < 4 ? 1 : 2) : 0;
            int luj = (cls & 1) ? (ju < 4 ? 1 : 2) : 0;
            int bidx = (jt - ju + 6) * 13 + (it - iu + 6);
            val = btab[bidx * 3 + hd] + ((li*3+lj) == (lui*3+luj) ? 0.f : -100.f);
        }
        bm[j] = val;
    }
}

// ---------- K1: gather + LN1(frag) + QKV MFMA GEMM -> qkvb bf16 (R12 form) ----------
#define LDH 104
extern "C" __global__ void __launch_bounds__(512, 4) k1_qkv(
    const float* __restrict__ x, const float* __restrict__ g1, const float* __restrict__ b1,
    const unsigned short* __restrict__ qwt, const float* __restrict__ qb,
    unsigned short* __restrict__ qkvb)
{
    __shared__ unsigned short Wc[96 * LDH];    // 19968 B
    const int tid = threadIdx.x, wave = tid >> 6, lane = tid & 63;
    const int l15 = lane & 15, g4 = lane >> 4;
    const int blk = blockIdx.x;

    s8v ha[3];
    {
        const int orig = wtok_to_orig(blk * 128 + wave * 16 + l15);
        ln_frag(x + (size_t)orig * CC, g1, b1, g4, ha);
    }

    for (int ck = 0; ck < 3; ++ck) {
        for (int i = tid; i < 96 * 12; i += 512) {
            int r = i / 12, k0 = (i - r * 12) * 8;
            *reinterpret_cast<s8v*>(&Wc[r * LDH + k0]) =
                *reinterpret_cast<const s8v*>(&qwt[(ck * 96 + r) * 96 + k0]);
        }
        __syncthreads();
        fx4 acc[6];
        #pragma unroll
        for (int nt = 0; nt < 6; ++nt) acc[nt] = (fx4){0.f,0.f,0.f,0.f};
        #pragma unroll
        for (int ks = 0; ks < 3; ++ks) {
            #pragma unroll
            for (int nt = 0; nt < 6; ++nt) {
                s8v b = *reinterpret_cast<const s8v*>(&Wc[(nt*16 + l15)*LDH + ks*32 + g4*8]);
                acc[nt] = MFMA16(ha[ks], b, acc[nt]);
            }
        }
        const int rowb = blk * 128 + wave * 16 + g4 * 4;
        const float qmul = (ck == 0) ? QKSCALE : 1.f;   // qb scale matches scaled qwt
        #pragma unroll
        for (int nt = 0; nt < 6; ++nt) {
            const int col = ck * 96 + nt * 16 + l15;
            const float qbc = qb[col] * qmul;
            #pragma unroll
            for (int r = 0; r < 4; ++r)
                qkvb[(size_t)(rowb + r) * 288 + col] = f2bf(acc[nt][r] + qbc);
        }
        __syncthreads();
    }
}

// ---------- K2: MFMA attention on bf16 qkv (R12 form) ----------
extern "C" __global__ void __launch_bounds__(64, 2) k2_attn(
    unsigned short* __restrict__ qkvb, const float* __restrict__ bm)
{
    __shared__ unsigned short P[64][72];   // 9216 B
    const int lane = threadIdx.x;
    const int l15 = lane & 15, g4 = lane >> 4;
    const int task = blockIdx.x;
    const int win = task / 3, h = task - win * 3;
    const int g0  = win * NTK;
    const int w   = win & 63;
    const int cls = (((w >> 3) == 7) ? 2 : 0) + (((w & 7) == 7) ? 1 : 0);
    const float* BMh = bm + ((size_t)(cls * 3 + h)) * 49 * 64;

    s8v aq[4], bk[4];
    #pragma unroll
    for (int mt = 0; mt < 4; ++mt) {
        int tok = mt * 16 + l15; if (tok > 48) tok = 48;
        const unsigned short* qp = &qkvb[(size_t)(g0 + tok) * 288 + h * HDM + g4 * 8];
        aq[mt] = *reinterpret_cast<const s8v*>(qp);        // Q (pre-scaled)
        bk[mt] = *reinterpret_cast<const s8v*>(qp + 96);   // K
    }

    fx4 sc[4][4];
    #pragma unroll
    for (int mt = 0; mt < 4; ++mt)
        #pragma unroll
        for (int nt = 0; nt < 4; ++nt)
            sc[mt][nt] = MFMA16(aq[mt], bk[nt], ((fx4){0.f,0.f,0.f,0.f}));

    #pragma unroll
    for (int mt = 0; mt < 4; ++mt) {
        #pragma unroll
        for (int r = 0; r < 4; ++r) {
            const int m = mt * 16 + g4 * 4 + r;
            const int mc = m > 48 ? 48 : m;
            float rs1 = 0.f;
            #pragma unroll
            for (int nt = 0; nt < 4; ++nt) {
                const int n = nt * 16 + l15;
                float s = sc[mt][nt][r] + BMh[mc * 64 + n];
                float e = (n < NTK) ? __expf(s) : 0.f;
                sc[mt][nt][r] = e;
                rs1 += e;
            }
            rs1 += __shfl_xor(rs1, 1); rs1 += __shfl_xor(rs1, 2);
            rs1 += __shfl_xor(rs1, 4); rs1 += __shfl_xor(rs1, 8);
            const float iv1 = 1.f / rs1;
            float rs2 = 0.f;
            #pragma unroll
            for (int nt = 0; nt < 4; ++nt) {
                const int n = nt * 16 + l15;
                float e2 = (n < NTK) ? __expf(sc[mt][nt][r] * iv1) : 0.f;
                sc[mt][nt][r] = e2;
                rs2 += e2;
            }
            rs2 += __shfl_xor(rs2, 1); rs2 += __shfl_xor(rs2, 2);
            rs2 += __shfl_xor(rs2, 4); rs2 += __shfl_xor(rs2, 8);
            const float iv2 = 1.f / rs2;
            #pragma unroll
            for (int nt = 0; nt < 4; ++nt)
                P[m][nt * 16 + l15] = f2bf(sc[mt][nt][r] * iv2);
        }
    }
    __syncthreads();

    fx4 oc[4][2];
    #pragma unroll
    for (int mt = 0; mt < 4; ++mt) { oc[mt][0] = (fx4){0.f,0.f,0.f,0.f}; oc[mt][1] = (fx4){0.f,0.f,0.f,0.f}; }
    #pragma unroll
    for (int ks = 0; ks < 2; ++ks) {
        s8v vb[2];
        #pragma unroll
        for (int nt = 0; nt < 2; ++nt) {
            union { s8v v; unsigned short u[8]; } pv;
            #pragma unroll
            for (int j = 0; j < 8; ++j) {
                int tok = ks * 32 + g4 * 8 + j; if (tok > 48) tok = 48;
                pv.u[j] = qkvb[(size_t)(g0 + tok) * 288 + 192 + h * HDM + nt * 16 + l15];
            }
            vb[nt] = pv.v;
        }
        #pragma unroll
        for (int mt = 0; mt < 4; ++mt) {
            s8v pa = *reinterpret_cast<const s8v*>(&P[mt * 16 + l15][ks * 32 + g4 * 8]);
            oc[mt][0] = MFMA16(pa, vb[0], oc[mt][0]);
            oc[mt][1] = MFMA16(pa, vb[1], oc[mt][1]);
        }
    }
    #pragma unroll
    for (int mt = 0; mt < 4; ++mt) {
        #pragma unroll
        for (int r = 0; r < 4; ++r) {
            const int m = mt * 16 + g4 * 4 + r;
            if (m < NTK) {
                qkvb[(size_t)(g0 + m) * 288 + h * HDM + l15]      = f2bf(oc[mt][0][r]);
                qkvb[(size_t)(g0 + m) * 288 + h * HDM + 16 + l15] = f2bf(oc[mt][1][r]);
            }
        }
    }
}

// ---------- K2b: proj GEMM; A-frags direct from qkvb; LDS = Wc (R12 form) ----------
extern "C" __global__ void __launch_bounds__(512, 4) k2b_proj(
    const unsigned short* __restrict__ qkvb, const unsigned short* __restrict__ pwt,
    const float* __restrict__ pb, const float* __restrict__ x, float* __restrict__ out)
{
    __shared__ unsigned short Wc[96 * LDH];    // 19968 B
    const int tid = threadIdx.x, wave = tid >> 6, lane = tid & 63;
    const int l15 = lane & 15, g4 = lane >> 4;
    const int blk = blockIdx.x;

    for (int i = tid; i < 96 * 12; i += 512) {
        int r = i / 12, k0 = (i - r * 12) * 8;
        *reinterpret_cast<s8v*>(&Wc[r * LDH + k0]) =
            *reinterpret_cast<const s8v*>(&pwt[r * 96 + k0]);
    }
    const unsigned short* arow = qkvb + (size_t)(blk * 128 + wave * 16 + l15) * 288 + g4 * 8;
    s8v a0 = *reinterpret_cast<const s8v*>(arow);
    s8v a1 = *reinterpret_cast<const s8v*>(arow + 32);
    s8v a2 = *reinterpret_cast<const s8v*>(arow + 64);
    __syncthreads();

    fx4 acc[6];
    #pragma unroll
    for (int nt = 0; nt < 6; ++nt) acc[nt] = (fx4){0.f,0.f,0.f,0.f};
    #pragma unroll
    for (int nt = 0; nt < 6; ++nt) {
        acc[nt] = MFMA16(a0, *reinterpret_cast<const s8v*>(&Wc[(nt*16 + l15)*LDH +  0 + g4*8]), acc[nt]);
        acc[nt] = MFMA16(a1, *reinterpret_cast<const s8v*>(&Wc[(nt*16 + l15)*LDH + 32 + g4*8]), acc[nt]);
        acc[nt] = MFMA16(a2, *reinterpret_cast<const s8v*>(&Wc[(nt*16 + l15)*LDH + 64 + g4*8]), acc[nt]);
    }
    int orig[4];
    #pragma unroll
    for (int r = 0; r < 4; ++r)
        orig[r] = wtok_to_orig(blk * 128 + wave * 16 + g4 * 4 + r);
    #pragma unroll
    for (int nt = 0; nt < 6; ++nt) {
        const int col = nt * 16 + l15;
        const float pbc = pb[col];
        #pragma unroll
        for (int r = 0; r < 4; ++r) {
            const size_t idx = (size_t)orig[r] * CC + col;
            out[idx] = acc[nt][r] + pbc + x[idx];
        }
    }
}

// ---------- K3: barrier-free MLP; weights streamed as frag-linear b128 loads ----------
// A-frags in registers (ln_frag), Ac wave-private LDS (9.2 KB), B-frags =
// coalesced 1KB global loads from L1/L2-resident w1f/w2f. ZERO barriers ->
// waves fully independent; compiler free to prefetch frags across ck.
#define LDA 72
extern "C" __global__ void __launch_bounds__(256, 3) k3_mlp(
    float* __restrict__ xio, const float* __restrict__ g2, const float* __restrict__ b2,
    const unsigned short* __restrict__ w1f, const float* __restrict__ bf1,
    const unsigned short* __restrict__ w2f, const float* __restrict__ bf2)
{
    __shared__ unsigned short Ac[64 * LDA];    // 9216 B, wave-private rows
    const int tid = threadIdx.x, wave = tid >> 6, lane = tid & 63;
    const int l15 = lane & 15, g4 = lane >> 4;
    const int row0 = blockIdx.x * 64 + wave * 16;

    s8v ha[3];
    ln_frag(xio + (size_t)(row0 + l15) * CC, g2, b2, g4, ha);

    fx4 oacc[6];
    #pragma unroll
    for (int nt = 0; nt < 6; ++nt) oacc[nt] = (fx4){0.f,0.f,0.f,0.f};

    for (int ck = 0; ck < 6; ++ck) {
        // fc1: B-frags contiguous per wave (1KB coalesced loads)
        fx4 a1[4];
        #pragma unroll
        for (int nt = 0; nt < 4; ++nt) a1[nt] = (fx4){0.f,0.f,0.f,0.f};
        #pragma unroll
        for (int ks = 0; ks < 3; ++ks) {
            #pragma unroll
            for (int nt = 0; nt < 4; ++nt) {
                s8v b = *reinterpret_cast<const s8v*>(
                    &w1f[(((ck * 4 + nt) * 3 + ks) * 64 + lane) * 8]);
                a1[nt] = MFMA16(ha[ks], b, a1[nt]);
            }
        }
        // gelu^2 -> Ac (wave-private: in-wave lgkmcnt ordering suffices)
        #pragma unroll
        for (int nt = 0; nt < 4; ++nt) {
            const float bb = bf1[ck * 64 + nt * 16 + l15];
            #pragma unroll
            for (int r = 0; r < 4; ++r) {
                float v0 = a1[nt][r] + bb;
                Ac[(wave*16 + g4*4 + r) * LDA + nt*16 + l15] = f2bf(gelu_t(gelu_t(v0)));
            }
        }
        // fc2
        #pragma unroll
        for (int ks = 0; ks < 2; ++ks) {
            s8v a = *reinterpret_cast<const s8v*>(&Ac[(wave*16 + l15)*LDA + ks*32 + g4*8]);
            #pragma unroll
            for (int nt = 0; nt < 6; ++nt) {
                s8v b = *reinterpret_cast<const s8v*>(
                    &w2f[(((ck * 6 + nt) * 2 + ks) * 64 + lane) * 8]);
                oacc[nt] = MFMA16(a, b, oacc[nt]);
            }
        }
    }

    const int rowb = row0 + g4 * 4;
    #pragma unroll
    for (int nt = 0; nt < 6; ++nt) {
        const int col = nt * 16 + l15;
        const float bb = bf2[col];
        #pragma unroll
        for (int r = 0; r < 4; ++r) {
            const size_t idx = (size_t)(rowb + r) * CC + col;
            xio[idx] = xio[idx] + oacc[nt][r] + bb;
        }
    }
}

extern "C" void kernel_launch(void* const* d_in, const int* in_sizes, int n_in,
                              void* d_out, int out_size, void* d_ws, size_t ws_size,
                              hipStream_t stream)
{
    const float* x    = (const float*)d_in[0];
    const float* n1g  = (const float*)d_in[1];
    const float* n1b  = (const float*)d_in[2];
    const float* qw   = (const float*)d_in[3];
    const float* qb   = (const float*)d_in[4];
    const float* btab = (const float*)d_in[5];
    const float* pw   = (const float*)d_in[6];
    const float* pb   = (const float*)d_in[7];
    const float* n2g  = (const float*)d_in[8];
    const float* n2b  = (const float*)d_in[9];
    const float* w1   = (const float*)d_in[10];
    const float* bf1  = (const float*)d_in[11];
    const float* w2   = (const float*)d_in[12];
    const float* bf2  = (const float*)d_in[13];
    float* out = (float*)d_out;

    unsigned short* qkvb = (unsigned short*)d_ws;                 // TOT*288 bf16 = 57.8 MB
    unsigned short* wbf = qkvb + (size_t)TOT * 288;
    unsigned short* qwt = wbf;                                    // 27648
    unsigned short* pwt = qwt + 27648;                            // 9216
    unsigned short* w1f = pwt + 9216;                             // 36864 frag-linear
    unsigned short* w2f = w1f + 36864;                            // 36864 frag-linear
    float* bmt = (float*)(wbf + 110592);                          // [4][3][49][64]

    p0_prep <<<579, 256, 0, stream>>>(qw, pw, w1, w2, btab, wbf);
    k1_qkv  <<<TOT/128, 512, 0, stream>>>(x, n1g, n1b, qwt, qb, qkvb);
    k2_attn <<<BB*NWIN*NHD, 64, 0, stream>>>(qkvb, bmt);
    k2b_proj<<<TOT/128, 512, 0, stream>>>(qkvb, pwt, pb, x, out);
    k3_mlp  <<<TOT/64, 256, 0, stream>>>(out, n2g, n2b, w1f, bf1, w2f, bf2);
}